// Round 3
// 9772.036 us; speedup vs baseline: 1.0287x; 1.0287x over previous
//
#include <hip/hip_runtime.h>

// Problem constants (from reference)
#define SEQ   8192
#define HID   256
#define G3    768      // 3*HID
#define TSTART 1024    // SEQ/8
#define NEGD  1365     // SEQ/6
#define TCNT  5791     // (SEQ - 10 - NEGD - 4 + 2) - TSTART
#define DENOMF 23164.0f // TCNT*4

typedef _Float16 half2_t __attribute__((ext_vector_type(2)));

__device__ __forceinline__ float fdot2(half2_t a, half2_t b, float c) {
#if __has_builtin(__builtin_amdgcn_fdot2)
  return __builtin_amdgcn_fdot2(a, b, c, false);
#else
  return c + (float)a.x * (float)b.x + (float)a.y * (float)b.y;
#endif
}

__device__ __forceinline__ half2_t h2_from_u32(unsigned int u) {
  return __builtin_bit_cast(half2_t, u);
}

__device__ __forceinline__ float sigmoidf_fast(float x) {
  return 1.0f / (1.0f + __expf(-x));
}
// tanh via sigmoid form: safe at both extremes (exp under/overflow -> +-1)
__device__ __forceinline__ float tanhf_fast(float x) {
  return 2.0f / (1.0f + __expf(-2.0f * x)) - 1.0f;
}

// Sum this lane's value with lane^32's value, for all 64 lanes.
// Uses __shfl_xor width-64 (ds_bpermute path) -- the SAME primitive the
// passing cpc/rnorm kernels use across the 32-lane boundary, so its
// semantics are harness-proven. (A permlane32_swap variant failed
// correctness in the previous round; do not reintroduce it without an
// isolated probe.)
__device__ __forceinline__ float khalf_sum(float x) {
  return x + __shfl_xor(x, 32, 64);
}

// ---------------------------------------------------------------------------
// init: zero the loss accumulators (ws is poisoned 0xAA every call)
// ---------------------------------------------------------------------------
__global__ void init_kernel(float* accum) {
  if (threadIdx.x < 2) accum[threadIdx.x] = 0.0f;
}

// ---------------------------------------------------------------------------
// Phase A: xW = data @ Wih^T + bih -> f32 [SEQ][768]. All f32.
// grid (256, 3), block 256. Thread owns output col o; 32-row x-tile in LDS.
// ---------------------------------------------------------------------------
__global__ __launch_bounds__(256) void xw_kernel(
    const float* __restrict__ data, const float* __restrict__ Wih,
    const float* __restrict__ bih, float* __restrict__ xw)
{
  __shared__ float4 xs4[32 * 64];   // 32 rows x 256 f32 = 32 KB
  const int o  = blockIdx.y * 256 + threadIdx.x;
  const int m0 = blockIdx.x * 32;

  float* xsf = (float*)xs4;
  for (int r = 0; r < 32; ++r)
    xsf[r * 256 + threadIdx.x] = data[(size_t)(m0 + r) * 256 + threadIdx.x];
  __syncthreads();

  const float b = bih[o];
  float acc[32];
#pragma unroll
  for (int r = 0; r < 32; ++r) acc[r] = b;

  const float4* wrow = (const float4*)(Wih + (size_t)o * 256);
  for (int kc = 0; kc < 4; ++kc) {
    float4 w[16];
#pragma unroll
    for (int j = 0; j < 16; ++j) w[j] = wrow[kc * 16 + j];
#pragma unroll
    for (int r = 0; r < 32; ++r) {
      const float4* xr = xs4 + r * 64 + kc * 16;
      float a0 = 0.f, a1 = 0.f, a2 = 0.f, a3 = 0.f;
#pragma unroll
      for (int j = 0; j < 4; ++j) {
        float4 x0 = xr[4 * j + 0], x1 = xr[4 * j + 1];
        float4 x2 = xr[4 * j + 2], x3 = xr[4 * j + 3];
        float4 w0 = w[4 * j + 0], w1 = w[4 * j + 1];
        float4 w2 = w[4 * j + 2], w3 = w[4 * j + 3];
        a0 = fmaf(w0.x, x0.x, fmaf(w0.y, x0.y, fmaf(w0.z, x0.z, fmaf(w0.w, x0.w, a0))));
        a1 = fmaf(w1.x, x1.x, fmaf(w1.y, x1.y, fmaf(w1.z, x1.z, fmaf(w1.w, x1.w, a1))));
        a2 = fmaf(w2.x, x2.x, fmaf(w2.y, x2.y, fmaf(w2.z, x2.z, fmaf(w2.w, x2.w, a2))));
        a3 = fmaf(w3.x, x3.x, fmaf(w3.y, x3.y, fmaf(w3.z, x3.z, fmaf(w3.w, x3.w, a3))));
      }
      acc[r] += (a0 + a1) + (a2 + a3);
    }
  }
  for (int r = 0; r < 32; ++r)
    xw[(size_t)(m0 + r) * G3 + o] = acc[r];
}

// ---------------------------------------------------------------------------
// data row norms: one wave per row (f32 data)
// ---------------------------------------------------------------------------
__global__ __launch_bounds__(256) void rnorm_kernel(
    const float* __restrict__ data, float* __restrict__ rn)
{
  int wave = threadIdx.x >> 6, lane = threadIdx.x & 63;
  int row = blockIdx.x * 4 + wave;
  const float* xr = data + (size_t)row * HID;
  float a = xr[lane], b = xr[lane + 64], c = xr[lane + 128], d = xr[lane + 192];
  float s = a * a + b * b + c * c + d * d;
#pragma unroll
  for (int off = 32; off; off >>= 1) s += __shfl_xor(s, off, 64);
  if (lane == 0) rn[row] = fmaxf(sqrtf(s), 1e-8f);
}

// ---------------------------------------------------------------------------
// Phase B: sequential GRU scan. ONE block, 512 threads (8 waves, 2/SIMD,
// 256-VGPR budget).
//
// The two k-halves of each output column live in the SAME wave
// (kh = lane>>5, column c = wave*32 + (lane&31)). Each thread holds
// 192 f16x2 weight VGPRs (3 gate rows x its 128-wide k-half); the
// cross-k reduction is a single in-wave lane^32 shuffle sum instead
// of an LDS partial exchange. Removes per step: 72 LDS instructions,
// one __syncthreads, and one ~130-cycle LDS round-trip on the serial
// critical path. h stays double-buffered as packed f16 in LDS;
// h-broadcast reads (16 x ds_read_b128 per wave, 2-address multicast
// = conflict-free) unchanged. ONE barrier per step.
// ---------------------------------------------------------------------------
__global__ __launch_bounds__(512, 2) void gru_kernel(
    const float* __restrict__ Whh, const float* __restrict__ bhh,
    const float* __restrict__ xw, float* __restrict__ zout)
{
  __shared__ uint4 hb[2][32];      // double-buffered h: 256 packed f16 each
  const int i    = threadIdx.x;
  const int wave = i >> 6;
  const int lane = i & 63;
  const int c    = wave * 32 + (lane & 31);  // output column (0..255)
  const int kh   = lane >> 5;                // k-half: [kh*128, kh*128+128)

  // --- load this thread's k-half of the 3 gate rows into f16x2 registers ---
  half2_t wr[64], wz[64], wn[64];
  {
    const float4* pr = (const float4*)(Whh + (size_t)c * 256 + kh * 128);
    const float4* pz = (const float4*)(Whh + (size_t)(256 + c) * 256 + kh * 128);
    const float4* pn = (const float4*)(Whh + (size_t)(512 + c) * 256 + kh * 128);
#pragma unroll
    for (int j = 0; j < 32; ++j) {
      float4 a = pr[j];
      half2_t p0; p0.x = (_Float16)a.x; p0.y = (_Float16)a.y;
      half2_t p1; p1.x = (_Float16)a.z; p1.y = (_Float16)a.w;
      wr[2 * j] = p0; wr[2 * j + 1] = p1;
    }
#pragma unroll
    for (int j = 0; j < 32; ++j) {
      float4 a = pz[j];
      half2_t p0; p0.x = (_Float16)a.x; p0.y = (_Float16)a.y;
      half2_t p1; p1.x = (_Float16)a.z; p1.y = (_Float16)a.w;
      wz[2 * j] = p0; wz[2 * j + 1] = p1;
    }
#pragma unroll
    for (int j = 0; j < 32; ++j) {
      float4 a = pn[j];
      half2_t p0; p0.x = (_Float16)a.x; p0.y = (_Float16)a.y;
      half2_t p1; p1.x = (_Float16)a.z; p1.y = (_Float16)a.w;
      wn[2 * j] = p0; wn[2 * j + 1] = p1;
    }
  }
  const float br = bhh[c], bz = bhh[256 + c], bn = bhh[512 + c];

  if (i < 32) hb[0][i] = make_uint4(0u, 0u, 0u, 0u);
  __syncthreads();

  float hreg = 0.0f;   // h[c], tracked redundantly by both kh copies
  float xr0 = xw[c], xz0 = xw[256 + c], xn0 = xw[512 + c];

  for (int s = 0; s < SEQ; ++s) {
    // issue next step's xW loads now (HBM/L2 latency hidden behind the dot)
    const size_t bnext = (size_t)(s + 1 < SEQ ? s + 1 : s) * G3;
    float xr1 = xw[bnext + c], xz1 = xw[bnext + 256 + c], xn1 = xw[bnext + 512 + c];

    // --- 3 half-row dots against this thread's k-half of h (LDS multicast) ---
    const uint4* hrow = hb[s & 1] + kh * 16;
    uint4 q[4];
#pragma unroll
    for (int p = 0; p < 4; ++p) q[p] = hrow[p];

    float ar0 = 0.f, ar1 = 0.f, az0 = 0.f, az1 = 0.f, an0 = 0.f, an1 = 0.f;
#pragma unroll
    for (int j = 0; j < 16; ++j) {
      uint4 cur = q[j & 3];
      if (j + 4 < 16) q[j & 3] = hrow[j + 4];
      half2_t hx = h2_from_u32(cur.x), hy = h2_from_u32(cur.y);
      half2_t hz = h2_from_u32(cur.z), hw = h2_from_u32(cur.w);
      ar0 = fdot2(wr[4 * j + 0], hx, ar0);
      ar1 = fdot2(wr[4 * j + 1], hy, ar1);
      ar0 = fdot2(wr[4 * j + 2], hz, ar0);
      ar1 = fdot2(wr[4 * j + 3], hw, ar1);
      az0 = fdot2(wz[4 * j + 0], hx, az0);
      az1 = fdot2(wz[4 * j + 1], hy, az1);
      az0 = fdot2(wz[4 * j + 2], hz, az0);
      az1 = fdot2(wz[4 * j + 3], hw, az1);
      an0 = fdot2(wn[4 * j + 0], hx, an0);
      an1 = fdot2(wn[4 * j + 1], hy, an1);
      an0 = fdot2(wn[4 * j + 2], hz, an0);
      an1 = fdot2(wn[4 * j + 3], hw, an1);
    }

    // --- cross-k reduce in-wave: lane^32 partner sum (no barrier) ---
    float ar = khalf_sum(ar0 + ar1);
    float az = khalf_sum(az0 + az1);
    float an = khalf_sum(an0 + an1);

    // --- gate math, redundantly in both kh copies (no divergence) ---
    float rg = sigmoidf_fast(ar + br + xr0);
    float zg = sigmoidf_fast(az + bz + xz0);
    float ng = tanhf_fast(xn0 + rg * (an + bn));
    hreg = (1.0f - zg) * ng + zg * hreg;

    if (kh == 0) {   // one copy publishes h + z (32 lanes/wave, contiguous)
      ((_Float16*)hb[(s + 1) & 1])[c] = (_Float16)hreg;
      zout[(size_t)s * HID + c] = hreg;
    }
    __syncthreads();
    xr0 = xr1; xz0 = xz1; xn0 = xn1;
  }
}

// ---------------------------------------------------------------------------
// Phase C: NCE loss + accuracy. One block per t, 4 waves = 4 timespans.
// Reads f32 z straight from d_out.
// ---------------------------------------------------------------------------
__global__ __launch_bounds__(256) void cpc_kernel(
    const float* __restrict__ x, const float* __restrict__ zf,
    const float* __restrict__ rn, float* __restrict__ accum)
{
  __shared__ float zsh[HID];
  __shared__ float wsum[4];
  __shared__ float nce_s[4], acc_s[4];
  const int tt = TSTART + blockIdx.x;
  const int i = threadIdx.x;
  const int wave = i >> 6, lane = i & 63;

  float zi = zf[(size_t)tt * HID + i];
  zsh[i] = zi;
  float p = zi * zi;
#pragma unroll
  for (int off = 32; off; off >>= 1) p += __shfl_xor(p, off, 64);
  if (lane == 0) wsum[wave] = p;
  __syncthreads();
  float zn = fmaxf(sqrtf(wsum[0] + wsum[1] + wsum[2] + wsum[3]), 1e-8f);

  float z0 = zsh[lane], z1 = zsh[lane + 64], z2 = zsh[lane + 128], z3 = zsh[lane + 192];
  const int base = tt + wave + 1;   // pos index for timespan (wave+1)

  float tot[10];
#pragma unroll
  for (int n = 0; n < 10; ++n) {
    int idx = base + (n > 0 ? (NEGD + n - 1) : 0);
    const float* xr = x + (size_t)idx * HID;
    float q = xr[lane] * z0 + xr[lane + 64] * z1 + xr[lane + 128] * z2 + xr[lane + 192] * z3;
#pragma unroll
    for (int off = 32; off; off >>= 1) q += __shfl_xor(q, off, 64);
    tot[n] = q / (rn[idx] * zn);
  }
  float m = tot[0];
#pragma unroll
  for (int n = 1; n < 10; ++n) m = fmaxf(m, tot[n]);
  float se = 0.f;
#pragma unroll
  for (int n = 0; n < 10; ++n) se += expf(tot[n] - m);
  float logp0 = (tot[0] - m) - logf(se);
  float accv = (tot[0] >= m) ? 1.0f : 0.0f;  // argmax==0 iff tot[0] is the max

  if (lane == 0) { nce_s[wave] = -logp0; acc_s[wave] = accv; }
  __syncthreads();
  if (i == 0) {
    atomicAdd(accum,     nce_s[0] + nce_s[1] + nce_s[2] + nce_s[3]);
    atomicAdd(accum + 1, acc_s[0] + acc_s[1] + acc_s[2] + acc_s[3]);
  }
}

__global__ void fin_kernel(const float* __restrict__ accum,
                           float* __restrict__ out)
{
  if (threadIdx.x == 0) {
    out[(size_t)SEQ * HID]     = accum[0] / DENOMF;   // nce
    out[(size_t)SEQ * HID + 1] = accum[1] / DENOMF;   // acc
  }
}

// ---------------------------------------------------------------------------
extern "C" void kernel_launch(void* const* d_in, const int* in_sizes, int n_in,
                              void* d_out, int out_size, void* d_ws, size_t ws_size,
                              hipStream_t stream)
{
  // Inputs are f32 (reference dtypes). Output f32: z [SEQ*HID] | nce | acc.
  const float* data = (const float*)d_in[0];
  const float* Wih  = (const float*)d_in[1];
  const float* Whh  = (const float*)d_in[2];
  const float* bih  = (const float*)d_in[3];
  const float* bhh  = (const float*)d_in[4];
  float* out = (float*)d_out;

  // ws layout: xw f32 [SEQ*768] 25.17MB | rn f32 [SEQ] | accum f32 [2]
  char* p = (char*)d_ws;
  float* xw    = (float*)p;  p += (size_t)SEQ * G3 * sizeof(float);
  float* rn    = (float*)p;  p += (size_t)SEQ * sizeof(float);
  float* accum = (float*)p;

  init_kernel<<<1, 64, 0, stream>>>(accum);
  xw_kernel<<<dim3(256, 3), 256, 0, stream>>>(data, Wih, bih, xw);
  rnorm_kernel<<<SEQ / 4, 256, 0, stream>>>(data, rn);
  gru_kernel<<<1, 512, 0, stream>>>(Whh, bhh, xw, out);
  cpc_kernel<<<TCNT, 256, 0, stream>>>(data, out, rn, accum);
  fin_kernel<<<1, 1, 0, stream>>>(accum, out);
}

// Round 4
// 8082.793 us; speedup vs baseline: 1.2437x; 1.2090x over previous
//
#include <hip/hip_runtime.h>

// Problem constants (from reference)
#define SEQ   8192
#define HID   256
#define G3    768      // 3*HID
#define TSTART 1024    // SEQ/8
#define NEGD  1365     // SEQ/6
#define TCNT  5791     // (SEQ - 10 - NEGD - 4 + 2) - TSTART
#define DENOMF 23164.0f // TCNT*4

typedef _Float16 half8_t __attribute__((ext_vector_type(8)));
typedef float    f32x4  __attribute__((ext_vector_type(4)));

__device__ __forceinline__ float sigmoidf_fast(float x) {
  return 1.0f / (1.0f + __expf(-x));
}
// tanh via sigmoid form: safe at both extremes (exp under/overflow -> +-1)
__device__ __forceinline__ float tanhf_fast(float x) {
  return 2.0f / (1.0f + __expf(-2.0f * x)) - 1.0f;
}

// ---------------------------------------------------------------------------
// init: zero the loss accumulators (ws is poisoned 0xAA every call)
// ---------------------------------------------------------------------------
__global__ void init_kernel(float* accum) {
  if (threadIdx.x < 2) accum[threadIdx.x] = 0.0f;
}

// ---------------------------------------------------------------------------
// Phase A: xW = data @ Wih^T + bih -> f32 [SEQ][768]. All f32.
// grid (256, 3), block 256. Thread owns output col o; 32-row x-tile in LDS.
// ---------------------------------------------------------------------------
__global__ __launch_bounds__(256) void xw_kernel(
    const float* __restrict__ data, const float* __restrict__ Wih,
    const float* __restrict__ bih, float* __restrict__ xw)
{
  __shared__ float4 xs4[32 * 64];   // 32 rows x 256 f32 = 32 KB
  const int o  = blockIdx.y * 256 + threadIdx.x;
  const int m0 = blockIdx.x * 32;

  float* xsf = (float*)xs4;
  for (int r = 0; r < 32; ++r)
    xsf[r * 256 + threadIdx.x] = data[(size_t)(m0 + r) * 256 + threadIdx.x];
  __syncthreads();

  const float b = bih[o];
  float acc[32];
#pragma unroll
  for (int r = 0; r < 32; ++r) acc[r] = b;

  const float4* wrow = (const float4*)(Wih + (size_t)o * 256);
  for (int kc = 0; kc < 4; ++kc) {
    float4 w[16];
#pragma unroll
    for (int j = 0; j < 16; ++j) w[j] = wrow[kc * 16 + j];
#pragma unroll
    for (int r = 0; r < 32; ++r) {
      const float4* xr = xs4 + r * 64 + kc * 16;
      float a0 = 0.f, a1 = 0.f, a2 = 0.f, a3 = 0.f;
#pragma unroll
      for (int j = 0; j < 4; ++j) {
        float4 x0 = xr[4 * j + 0], x1 = xr[4 * j + 1];
        float4 x2 = xr[4 * j + 2], x3 = xr[4 * j + 3];
        float4 w0 = w[4 * j + 0], w1 = w[4 * j + 1];
        float4 w2 = w[4 * j + 2], w3 = w[4 * j + 3];
        a0 = fmaf(w0.x, x0.x, fmaf(w0.y, x0.y, fmaf(w0.z, x0.z, fmaf(w0.w, x0.w, a0))));
        a1 = fmaf(w1.x, x1.x, fmaf(w1.y, x1.y, fmaf(w1.z, x1.z, fmaf(w1.w, x1.w, a1))));
        a2 = fmaf(w2.x, x2.x, fmaf(w2.y, x2.y, fmaf(w2.z, x2.z, fmaf(w2.w, x2.w, a2))));
        a3 = fmaf(w3.x, x3.x, fmaf(w3.y, x3.y, fmaf(w3.z, x3.z, fmaf(w3.w, x3.w, a3))));
      }
      acc[r] += (a0 + a1) + (a2 + a3);
    }
  }
  for (int r = 0; r < 32; ++r)
    xw[(size_t)(m0 + r) * G3 + o] = acc[r];
}

// ---------------------------------------------------------------------------
// data row norms: one wave per row (f32 data)
// ---------------------------------------------------------------------------
__global__ __launch_bounds__(256) void rnorm_kernel(
    const float* __restrict__ data, float* __restrict__ rn)
{
  int wave = threadIdx.x >> 6, lane = threadIdx.x & 63;
  int row = blockIdx.x * 4 + wave;
  const float* xr = data + (size_t)row * HID;
  float a = xr[lane], b = xr[lane + 64], c = xr[lane + 128], d = xr[lane + 192];
  float s = a * a + b * b + c * c + d * d;
#pragma unroll
  for (int off = 32; off; off >>= 1) s += __shfl_xor(s, off, 64);
  if (lane == 0) rn[row] = fmaxf(sqrtf(s), 1e-8f);
}

// ---------------------------------------------------------------------------
// Phase B: sequential GRU scan via MFMA matvec. ONE block, 512 threads
// (8 waves, 2/SIMD).
//
// Per step: y(768) = Whh @ h(256). Wave w owns output columns
// w*32..w*32+31 for ALL THREE gates: 6 row-tiles of 16 (gate G x col-half
// t2), K = 8 chunks of 32 -> 48 mfma_f32_16x16x32_f16 per wave per step.
// Weights stay RESIDENT as A-fragments (48 x half8 = 192 VGPRs; A-frag:
// row = lane&15, k = (lane>>4)*8 + j). h is broadcast into ALL 16 B
// columns (B-frag = h[k-range], independent of lane&15), so every C
// column equals y: each lane holds y for rows (lane>>4)*4+reg of its 6
// tiles with NO cross-lane redistribution. Any consistent k-mapping is
// exactly correct for matvec (A/B k-permutations cancel); the only
// layout-critical facts are the m89-verified C mapping
// (col=lane&15, row=(lane>>4)*4+reg) and A row=lane&15.
//
// Gate math: lane (g=lane>>4, jsel=lane&7) finalizes ONE column
// c = w*32 + (jsel>>2)*16 + g*4 + (jsel&3), selecting its y_r/y_z/y_n
// from the 8 replicated candidates via a 7-cndmask tree (avoids 16x
// redundant transcendentals). Lanes with (lane&15)<8 publish h (f16,
// double-buffered LDS) and z (f32, global). ONE barrier per step.
// ---------------------------------------------------------------------------
__global__ __launch_bounds__(512, 2) void gru_kernel(
    const float* __restrict__ Whh, const float* __restrict__ bhh,
    const float* __restrict__ xw, float* __restrict__ zout)
{
  __shared__ _Float16 hbuf[2][HID];   // double-buffered h, 512 B each
  const int i    = threadIdx.x;
  const int wave = i >> 6;
  const int lane = i & 63;
  const int g    = lane >> 4;          // lane group: C-rows g*4..g*4+3, k-sub g*8..+8
  const int r16  = lane & 15;          // A-fragment row within a 16-row tile
  const int jsel = lane & 7;           // which (t2,reg) this lane finalizes
  const int c    = wave * 32 + (jsel >> 2) * 16 + g * 4 + (jsel & 3);
  const bool writer = (lane & 15) < 8; // one finalizer copy publishes

  // --- stage resident A-fragments: [gate*2 + t2][kc], 192 VGPRs ---
  half8_t A[6][8];
#pragma unroll
  for (int G = 0; G < 3; ++G)
#pragma unroll
    for (int t2 = 0; t2 < 2; ++t2) {
      const int row = G * 256 + wave * 32 + t2 * 16 + r16;
      const float* wp = Whh + (size_t)row * 256 + g * 8;
#pragma unroll
      for (int kc = 0; kc < 8; ++kc) {
        const float4* w4 = (const float4*)(wp + kc * 32);
        float4 u = w4[0], v = w4[1];
        half8_t f;
        f[0] = (_Float16)u.x; f[1] = (_Float16)u.y;
        f[2] = (_Float16)u.z; f[3] = (_Float16)u.w;
        f[4] = (_Float16)v.x; f[5] = (_Float16)v.y;
        f[6] = (_Float16)v.z; f[7] = (_Float16)v.w;
        A[G * 2 + t2][kc] = f;
      }
    }

  const float br = bhh[c], bz = bhh[256 + c], bn = bhh[512 + c];
  const bool s0 = (jsel & 1) != 0, s1 = (jsel & 2) != 0, s2 = (jsel & 4) != 0;

  if (i < HID) hbuf[0][i] = (_Float16)0.0f;
  __syncthreads();

  float hreg = 0.0f;   // own column's h, tracked in f32 (both writer copies)
  float xr0 = xw[c], xz0 = xw[256 + c], xn0 = xw[512 + c];

  const f32x4 zf = {0.f, 0.f, 0.f, 0.f};

  for (int s = 0; s < SEQ; ++s) {
    // issue next step's xW loads now (latency hidden behind the MFMAs)
    const size_t bnext = (size_t)(s + 1 < SEQ ? s + 1 : s) * G3;
    float xr1 = xw[bnext + c], xz1 = xw[bnext + 256 + c], xn1 = xw[bnext + 512 + c];

    const _Float16* hc = hbuf[s & 1];

    // --- 48 MFMAs: 6 tiles x 8 k-chunks, depth-1 B-frag prefetch ---
    f32x4 acc[6];
    half8_t bq = *(const half8_t*)(hc + g * 8);            // kc = 0
    half8_t bp = *(const half8_t*)(hc + 32 + g * 8);       // kc = 1
#pragma unroll
    for (int t = 0; t < 6; ++t)
      acc[t] = __builtin_amdgcn_mfma_f32_16x16x32_f16(A[t][0], bq, zf, 0, 0, 0);
    bq = bp;
#pragma unroll
    for (int kc = 1; kc < 8; ++kc) {
      half8_t bn2;
      if (kc < 7) bn2 = *(const half8_t*)(hc + (kc + 1) * 32 + g * 8);
#pragma unroll
      for (int t = 0; t < 6; ++t)
        acc[t] = __builtin_amdgcn_mfma_f32_16x16x32_f16(A[t][kc], bq, acc[t], 0, 0, 0);
      if (kc < 7) bq = bn2;
    }

    // --- select this lane's column from the 8 replicated candidates ---
    // y for (t2,reg): tile G*2+t2, acc reg = jsel&3; 7 cndmask per gate.
#define SEL8(x, y, out) do {                       \
      float p0 = s0 ? (x)[1] : (x)[0];             \
      float p1 = s0 ? (x)[3] : (x)[2];             \
      float p2 = s0 ? (y)[1] : (y)[0];             \
      float p3 = s0 ? (y)[3] : (y)[2];             \
      float q0 = s1 ? p1 : p0;                     \
      float q1 = s1 ? p3 : p2;                     \
      out = s2 ? q1 : q0;                          \
    } while (0)
    float yr, yz, yn;
    SEL8(acc[0], acc[1], yr);
    SEL8(acc[2], acc[3], yz);
    SEL8(acc[4], acc[5], yn);
#undef SEL8

    // --- gate math for the one owned column (f32) ---
    float rg = sigmoidf_fast(yr + br + xr0);
    float zg = sigmoidf_fast(yz + bz + xz0);
    float ng = tanhf_fast(xn0 + rg * (yn + bn));
    hreg = (1.0f - zg) * ng + zg * hreg;

    if (writer) {
      hbuf[(s + 1) & 1][c] = (_Float16)hreg;
      zout[(size_t)s * HID + c] = hreg;
    }
    __syncthreads();
    xr0 = xr1; xz0 = xz1; xn0 = xn1;
  }
}

// ---------------------------------------------------------------------------
// Phase C: NCE loss + accuracy. One block per t, 4 waves = 4 timespans.
// Reads f32 z straight from d_out.
// ---------------------------------------------------------------------------
__global__ __launch_bounds__(256) void cpc_kernel(
    const float* __restrict__ x, const float* __restrict__ zf,
    const float* __restrict__ rn, float* __restrict__ accum)
{
  __shared__ float zsh[HID];
  __shared__ float wsum[4];
  __shared__ float nce_s[4], acc_s[4];
  const int tt = TSTART + blockIdx.x;
  const int i = threadIdx.x;
  const int wave = i >> 6, lane = i & 63;

  float zi = zf[(size_t)tt * HID + i];
  zsh[i] = zi;
  float p = zi * zi;
#pragma unroll
  for (int off = 32; off; off >>= 1) p += __shfl_xor(p, off, 64);
  if (lane == 0) wsum[wave] = p;
  __syncthreads();
  float zn = fmaxf(sqrtf(wsum[0] + wsum[1] + wsum[2] + wsum[3]), 1e-8f);

  float z0 = zsh[lane], z1 = zsh[lane + 64], z2 = zsh[lane + 128], z3 = zsh[lane + 192];
  const int base = tt + wave + 1;   // pos index for timespan (wave+1)

  float tot[10];
#pragma unroll
  for (int n = 0; n < 10; ++n) {
    int idx = base + (n > 0 ? (NEGD + n - 1) : 0);
    const float* xr = x + (size_t)idx * HID;
    float q = xr[lane] * z0 + xr[lane + 64] * z1 + xr[lane + 128] * z2 + xr[lane + 192] * z3;
#pragma unroll
    for (int off = 32; off; off >>= 1) q += __shfl_xor(q, off, 64);
    tot[n] = q / (rn[idx] * zn);
  }
  float m = tot[0];
#pragma unroll
  for (int n = 1; n < 10; ++n) m = fmaxf(m, tot[n]);
  float se = 0.f;
#pragma unroll
  for (int n = 0; n < 10; ++n) se += expf(tot[n] - m);
  float logp0 = (tot[0] - m) - logf(se);
  float accv = (tot[0] >= m) ? 1.0f : 0.0f;  // argmax==0 iff tot[0] is the max

  if (lane == 0) { nce_s[wave] = -logp0; acc_s[wave] = accv; }
  __syncthreads();
  if (i == 0) {
    atomicAdd(accum,     nce_s[0] + nce_s[1] + nce_s[2] + nce_s[3]);
    atomicAdd(accum + 1, acc_s[0] + acc_s[1] + acc_s[2] + acc_s[3]);
  }
}

__global__ void fin_kernel(const float* __restrict__ accum,
                           float* __restrict__ out)
{
  if (threadIdx.x == 0) {
    out[(size_t)SEQ * HID]     = accum[0] / DENOMF;   // nce
    out[(size_t)SEQ * HID + 1] = accum[1] / DENOMF;   // acc
  }
}

// ---------------------------------------------------------------------------
extern "C" void kernel_launch(void* const* d_in, const int* in_sizes, int n_in,
                              void* d_out, int out_size, void* d_ws, size_t ws_size,
                              hipStream_t stream)
{
  // Inputs are f32 (reference dtypes). Output f32: z [SEQ*HID] | nce | acc.
  const float* data = (const float*)d_in[0];
  const float* Wih  = (const float*)d_in[1];
  const float* Whh  = (const float*)d_in[2];
  const float* bih  = (const float*)d_in[3];
  const float* bhh  = (const float*)d_in[4];
  float* out = (float*)d_out;

  // ws layout: xw f32 [SEQ*768] 25.17MB | rn f32 [SEQ] | accum f32 [2]
  char* p = (char*)d_ws;
  float* xw    = (float*)p;  p += (size_t)SEQ * G3 * sizeof(float);
  float* rn    = (float*)p;  p += (size_t)SEQ * sizeof(float);
  float* accum = (float*)p;

  init_kernel<<<1, 64, 0, stream>>>(accum);
  xw_kernel<<<dim3(256, 3), 256, 0, stream>>>(data, Wih, bih, xw);
  rnorm_kernel<<<SEQ / 4, 256, 0, stream>>>(data, rn);
  gru_kernel<<<1, 512, 0, stream>>>(Whh, bhh, xw, out);
  cpc_kernel<<<TCNT, 256, 0, stream>>>(data, out, rn, accum);
  fin_kernel<<<1, 1, 0, stream>>>(accum, out);
}